// Round 1
// baseline (2261.689 us; speedup 1.0000x reference)
//
#include <hip/hip_runtime.h>

#define B_ 16
#define N_ 4096
#define S_ 1024
#define K_ 32
#define R_ (B_*S_*K_)   // 524288 rows
#define NBLK_ (R_/64)   // 8192 row-tiles of 64

// ---------------------------------------------------------------- FPS
// one block per batch, 1024 threads, 4 points/thread, f64 distances
__global__ __launch_bounds__(1024) void fps_kernel(const float* __restrict__ xyz,
                                                   float* __restrict__ out0) {
    const int b = blockIdx.x;
    const int tid = threadIdx.x;
    __shared__ float xs[N_], ys[N_], zs[N_];
    __shared__ double wval[16];
    __shared__ int widx[16];
    __shared__ int far_sh;
    const float* xb = xyz + (size_t)b * 3 * N_;

    float px[4], py[4], pz[4];
    double dist[4];
#pragma unroll
    for (int j = 0; j < 4; ++j) {
        int i = tid + j * 1024;
        float x = xb[i], y = xb[N_ + i], z = xb[2 * N_ + i];
        xs[i] = x; ys[i] = y; zs[i] = z;
        px[j] = x; py[j] = y; pz[j] = z;
        dist[j] = 1e10;
    }
    __syncthreads();

    int far = 0;
    if (tid == 0) {
        out0[(size_t)b * 3072 + 0]    = xs[0];
        out0[(size_t)b * 3072 + 1024] = ys[0];
        out0[(size_t)b * 3072 + 2048] = zs[0];
    }
    for (int s = 1; s < S_; ++s) {
        double cx = (double)xs[far], cy = (double)ys[far], cz = (double)zs[far];
        double bv = -1.0; int bi = 0x7fffffff;
#pragma unroll
        for (int j = 0; j < 4; ++j) {
            double dx = (double)px[j] - cx;
            double dy = (double)py[j] - cy;
            double dz = (double)pz[j] - cz;
            double d = dx * dx + dy * dy + dz * dz;
            double nd = dist[j] < d ? dist[j] : d;
            dist[j] = nd;
            int gi = tid + j * 1024;
            if (nd > bv || (nd == bv && gi < bi)) { bv = nd; bi = gi; }
        }
        // wave butterfly (max value, min index on tie)
#pragma unroll
        for (int m = 1; m < 64; m <<= 1) {
            double ov = __shfl_xor(bv, m, 64);
            int    oi = __shfl_xor(bi, m, 64);
            if (ov > bv || (ov == bv && oi < bi)) { bv = ov; bi = oi; }
        }
        int wid = tid >> 6;
        if ((tid & 63) == 0) { wval[wid] = bv; widx[wid] = bi; }
        __syncthreads();
        if (tid < 16) {
            bv = wval[tid]; bi = widx[tid];
#pragma unroll
            for (int m = 1; m < 16; m <<= 1) {
                double ov = __shfl_xor(bv, m, 64);
                int    oi = __shfl_xor(bi, m, 64);
                if (ov > bv || (ov == bv && oi < bi)) { bv = ov; bi = oi; }
            }
            if (tid == 0) {
                far_sh = bi;
                out0[(size_t)b * 3072 + s]        = xs[bi];
                out0[(size_t)b * 3072 + 1024 + s] = ys[bi];
                out0[(size_t)b * 3072 + 2048 + s] = zs[bi];
            }
        }
        __syncthreads();
        far = far_sh;
    }
}

// ---------------------------------------------------------------- ball query
// one wave per centroid; first-32-ascending-index semantics via ballot compaction
__global__ __launch_bounds__(256) void ballq_kernel(const float* __restrict__ xyz,
                                                    const float* __restrict__ out0,
                                                    int* __restrict__ idxbuf) {
    int wid = threadIdx.x >> 6, lane = threadIdx.x & 63;
    int m = blockIdx.x * 4 + wid;          // centroid id < 16384
    int b = m >> 10, s = m & 1023;
    const float* xb = xyz + (size_t)b * 3 * N_;
    double cx = (double)out0[b * 3072 + s];
    double cy = (double)out0[b * 3072 + 1024 + s];
    double cz = (double)out0[b * 3072 + 2048 + s];
    double c2 = cx * cx + cy * cy + cz * cz;
    const double rr = 0.4 * 0.4;
    int* ob = idxbuf + (size_t)m * K_;
    int cnt = 0, first = -1;
    for (int ch = 0; ch < N_ / 64; ++ch) {
        int i = ch * 64 + lane;
        double x = (double)xb[i], y = (double)xb[N_ + i], z = (double)xb[2 * N_ + i];
        double p2 = x * x + y * y + z * z;
        double dot = cx * x + cy * y + cz * z;
        double sqr = (c2 + p2) - 2.0 * dot;
        bool in = !(sqr > rr);
        unsigned long long mask = __ballot(in);
        if (in) {
            int pos = cnt + __popcll(mask & ((1ull << lane) - 1ull));
            if (pos < K_) ob[pos] = i;
        }
        if (cnt == 0 && mask) first = ch * 64 + (__ffsll((long long)mask) - 1);
        cnt += __popcll(mask);
        if (cnt >= K_) break;
    }
    if (cnt < K_ && lane >= cnt && lane < K_) ob[lane] = first;
}

// ---------------------------------------------------------------- gather + layer0 stats
__global__ __launch_bounds__(256) void gather_stats0(
        const float* __restrict__ xyz, const float* __restrict__ pts,
        const float* __restrict__ out0, const int* __restrict__ idxbuf,
        const float* __restrict__ W0, const float* __restrict__ b0,
        float* __restrict__ F, float2* __restrict__ part) {
    __shared__ float Fs[64][6];
    __shared__ float W0s[384];
    __shared__ float b0s[64];
    __shared__ float2 red[4][64];
    int tid = threadIdx.x;
    long rowbase = (long)blockIdx.x * 64;
    if (tid < 64) {
        long r = rowbase + tid;
        int b = (int)(r >> 15);
        int rem = (int)(r & 32767);
        int s = rem >> 5;
        int i = idxbuf[r];
        const float* xb = xyz + (size_t)b * 3 * N_;
        const float* pb = pts + (size_t)b * 3 * N_;
        float cx = out0[b * 3072 + s], cy = out0[b * 3072 + 1024 + s], cz = out0[b * 3072 + 2048 + s];
        float f[6];
        f[0] = xb[i] - cx; f[1] = xb[N_ + i] - cy; f[2] = xb[2 * N_ + i] - cz;
        f[3] = pb[i];      f[4] = pb[N_ + i];      f[5] = pb[2 * N_ + i];
        float* Fg = F + (size_t)r * 6;
#pragma unroll
        for (int c = 0; c < 6; ++c) { Fs[tid][c] = f[c]; Fg[c] = f[c]; }
        b0s[tid] = b0[tid];
    }
    for (int t = tid; t < 384; t += 256) W0s[t] = W0[t];
    __syncthreads();
    int o = tid & 63, rg = tid >> 6;
    float w[6];
#pragma unroll
    for (int c = 0; c < 6; ++c) w[c] = W0s[o * 6 + c];
    float sum = 0.f, sq = 0.f;
#pragma unroll
    for (int rr = 0; rr < 16; ++rr) {
        int rl = rg * 16 + rr;
        float y = b0s[o];
#pragma unroll
        for (int c = 0; c < 6; ++c) y += Fs[rl][c] * w[c];
        sum += y; sq += y * y;
    }
    red[rg][o] = make_float2(sum, sq);
    __syncthreads();
    if (tid < 64) {
        float2 t0 = red[0][tid], t1 = red[1][tid], t2 = red[2][tid], t3 = red[3][tid];
        part[(size_t)blockIdx.x * 64 + tid] =
            make_float2(t0.x + t1.x + t2.x + t3.x, t0.y + t1.y + t2.y + t3.y);
    }
}

// ---------------------------------------------------------------- BN stats reduce
__global__ __launch_bounds__(256) void reduce_stats(const float2* __restrict__ part,
                                                    int nblk, int C,
                                                    const float* __restrict__ g,
                                                    const float* __restrict__ beta,
                                                    float* __restrict__ scale,
                                                    float* __restrict__ shift) {
    int o = blockIdx.x;
    int tid = threadIdx.x;
    double s = 0.0, q = 0.0;
    for (int i = tid; i < nblk; i += 256) {
        float2 v = part[(size_t)i * C + o];
        s += (double)v.x; q += (double)v.y;
    }
    __shared__ double ss[256], qq[256];
    ss[tid] = s; qq[tid] = q;
    __syncthreads();
    for (int m = 128; m > 0; m >>= 1) {
        if (tid < m) { ss[tid] += ss[tid + m]; qq[tid] += qq[tid + m]; }
        __syncthreads();
    }
    if (tid == 0) {
        const double Rd = (double)R_;
        double mean = ss[0] / Rd;
        double var = qq[0] / Rd - mean * mean;
        double sc = (double)g[o] / sqrt(var + 1e-5);
        scale[o] = (float)sc;
        shift[o] = (float)((double)beta[o] - mean * sc);
    }
}

// ---------------------------------------------------------------- layer1 GEMM (recompute layer0 + BN0 + relu)
__global__ __launch_bounds__(256) void layer1_kernel(
        const float* __restrict__ F, const float* __restrict__ W0,
        const float* __restrict__ b0, const float* __restrict__ scale0,
        const float* __restrict__ shift0, const float* __restrict__ W1,
        const float* __restrict__ b1, float* __restrict__ Y1,
        float2* __restrict__ part) {
    __shared__ float Fs[64][6];
    __shared__ float W0s[384];
    __shared__ float b0s[64], sc0[64], sh0[64];
    __shared__ float Xs[64][68];
    __shared__ float W1s[64][68];
    __shared__ float2 red[16][64];
    int tid = threadIdx.x;
    long rowbase = (long)blockIdx.x * 64;
    for (int t = tid; t < 384; t += 256) { Fs[t / 6][t % 6] = F[rowbase * 6 + t]; W0s[t] = W0[t]; }
    if (tid < 64) { b0s[tid] = b0[tid]; sc0[tid] = scale0[tid]; sh0[tid] = shift0[tid]; }
    for (int t = tid; t < 4096; t += 256) { int o = t >> 6, c = t & 63; W1s[c][o] = W1[t]; }
    __syncthreads();
    {
        int o = tid & 63, rg = tid >> 6;
        float w[6];
#pragma unroll
        for (int c = 0; c < 6; ++c) w[c] = W0s[o * 6 + c];
        float sc = sc0[o], sh = sh0[o], bb = b0s[o];
#pragma unroll
        for (int rr = 0; rr < 16; ++rr) {
            int rl = rg * 16 + rr;
            float y = bb;
#pragma unroll
            for (int c = 0; c < 6; ++c) y += Fs[rl][c] * w[c];
            Xs[rl][o] = fmaxf(sc * y + sh, 0.f);
        }
    }
    __syncthreads();
    int cg = tid & 15, rgp = tid >> 4;   // cols cg*4.., rows rgp*4..
    float acc[4][4] = {};
    for (int c = 0; c < 64; ++c) {
        float xr[4];
#pragma unroll
        for (int rr = 0; rr < 4; ++rr) xr[rr] = Xs[rgp * 4 + rr][c];
        float4 wv = *(const float4*)&W1s[c][cg * 4];
#pragma unroll
        for (int rr = 0; rr < 4; ++rr) {
            acc[rr][0] += xr[rr] * wv.x; acc[rr][1] += xr[rr] * wv.y;
            acc[rr][2] += xr[rr] * wv.z; acc[rr][3] += xr[rr] * wv.w;
        }
    }
    float bb1[4];
#pragma unroll
    for (int cc = 0; cc < 4; ++cc) bb1[cc] = b1[cg * 4 + cc];
#pragma unroll
    for (int rr = 0; rr < 4; ++rr)
#pragma unroll
        for (int cc = 0; cc < 4; ++cc) acc[rr][cc] += bb1[cc];
    // write Y1
#pragma unroll
    for (int rr = 0; rr < 4; ++rr) {
        long r = rowbase + rgp * 4 + rr;
        float4 v = make_float4(acc[rr][0], acc[rr][1], acc[rr][2], acc[rr][3]);
        *(float4*)&Y1[r * 64 + cg * 4] = v;
    }
    // stats
#pragma unroll
    for (int cc = 0; cc < 4; ++cc) {
        float s = acc[0][cc] + acc[1][cc] + acc[2][cc] + acc[3][cc];
        float q = acc[0][cc] * acc[0][cc] + acc[1][cc] * acc[1][cc] +
                  acc[2][cc] * acc[2][cc] + acc[3][cc] * acc[3][cc];
        red[rgp][cg * 4 + cc] = make_float2(s, q);
    }
    __syncthreads();
    if (tid < 64) {
        float s = 0.f, q = 0.f;
#pragma unroll
        for (int rp = 0; rp < 16; ++rp) { float2 v = red[rp][tid]; s += v.x; q += v.y; }
        part[(size_t)blockIdx.x * 64 + tid] = make_float2(s, q);
    }
}

// ---------------------------------------------------------------- layer2 GEMM + per-(b,s) max/min + stats
__global__ __launch_bounds__(256) void layer2_kernel(
        const float* __restrict__ Y1, const float* __restrict__ scale1,
        const float* __restrict__ shift1, const float* __restrict__ W2,
        const float* __restrict__ b2, float* __restrict__ gmax,
        float* __restrict__ gmin, float2* __restrict__ part) {
    __shared__ float Xs[64][68];
    __shared__ float W2s[64][132];
    __shared__ float red[16][128];
    int tid = threadIdx.x;
    long rowbase = (long)blockIdx.x * 64;
    {
        int o = tid & 63, rg = tid >> 6;
        float sc = scale1[o], sh = shift1[o];
#pragma unroll
        for (int rr = 0; rr < 16; ++rr) {
            int rl = rg * 16 + rr;
            float y = Y1[(rowbase + rl) * 64 + o];
            Xs[rl][o] = fmaxf(sc * y + sh, 0.f);
        }
    }
    for (int t = tid; t < 8192; t += 256) { int o = t >> 6, c = t & 63; W2s[c][o] = W2[t]; }
    __syncthreads();
    int cg = tid & 15, rgp = tid >> 4;   // cols cg*8.., rows rgp*4..
    float acc[4][8] = {};
    for (int c = 0; c < 64; ++c) {
        float xr[4];
#pragma unroll
        for (int rr = 0; rr < 4; ++rr) xr[rr] = Xs[rgp * 4 + rr][c];
        float4 wa = *(const float4*)&W2s[c][cg * 8];
        float4 wb = *(const float4*)&W2s[c][cg * 8 + 4];
#pragma unroll
        for (int rr = 0; rr < 4; ++rr) {
            acc[rr][0] += xr[rr] * wa.x; acc[rr][1] += xr[rr] * wa.y;
            acc[rr][2] += xr[rr] * wa.z; acc[rr][3] += xr[rr] * wa.w;
            acc[rr][4] += xr[rr] * wb.x; acc[rr][5] += xr[rr] * wb.y;
            acc[rr][6] += xr[rr] * wb.z; acc[rr][7] += xr[rr] * wb.w;
        }
    }
#pragma unroll
    for (int j = 0; j < 8; ++j) {
        float bb = b2[cg * 8 + j];
#pragma unroll
        for (int rr = 0; rr < 4; ++rr) acc[rr][j] += bb;
    }
    // ---- pass 1: sum
#pragma unroll
    for (int j = 0; j < 8; ++j)
        red[rgp][cg * 8 + j] = acc[0][j] + acc[1][j] + acc[2][j] + acc[3][j];
    __syncthreads();
    float psum = 0.f;
    if (tid < 128) { for (int rp = 0; rp < 16; ++rp) psum += red[rp][tid]; }
    __syncthreads();
    // ---- pass 2: sumsq
#pragma unroll
    for (int j = 0; j < 8; ++j)
        red[rgp][cg * 8 + j] = acc[0][j] * acc[0][j] + acc[1][j] * acc[1][j] +
                               acc[2][j] * acc[2][j] + acc[3][j] * acc[3][j];
    __syncthreads();
    if (tid < 128) {
        float psq = 0.f;
        for (int rp = 0; rp < 16; ++rp) psq += red[rp][tid];
        part[(size_t)blockIdx.x * 128 + tid] = make_float2(psum, psq);
    }
    __syncthreads();
    // ---- pass 3: max (rows of one thread all lie in one k-group)
#pragma unroll
    for (int j = 0; j < 8; ++j)
        red[rgp][cg * 8 + j] = fmaxf(fmaxf(acc[0][j], acc[1][j]), fmaxf(acc[2][j], acc[3][j]));
    __syncthreads();
    {
        int gsel = tid >> 7, col = tid & 127;
        float mv = -3.0e38f;
        for (int rp = gsel * 8; rp < gsel * 8 + 8; ++rp) mv = fmaxf(mv, red[rp][col]);
        gmax[((size_t)blockIdx.x * 2 + gsel) * 128 + col] = mv;
    }
    __syncthreads();
    // ---- pass 4: min
#pragma unroll
    for (int j = 0; j < 8; ++j)
        red[rgp][cg * 8 + j] = fminf(fminf(acc[0][j], acc[1][j]), fminf(acc[2][j], acc[3][j]));
    __syncthreads();
    {
        int gsel = tid >> 7, col = tid & 127;
        float mv = 3.0e38f;
        for (int rp = gsel * 8; rp < gsel * 8 + 8; ++rp) mv = fminf(mv, red[rp][col]);
        gmin[((size_t)blockIdx.x * 2 + gsel) * 128 + col] = mv;
    }
}

// ---------------------------------------------------------------- final BN2 + relu + transpose
__global__ __launch_bounds__(256) void final_kernel(const float* __restrict__ gmax,
                                                    const float* __restrict__ gmin,
                                                    const float* __restrict__ scale2,
                                                    const float* __restrict__ shift2,
                                                    float* __restrict__ out1) {
    int b = blockIdx.x, st = blockIdx.y, ot = blockIdx.z;
    __shared__ float tile[32][33];
    int tid = threadIdx.x;
    for (int e = tid; e < 1024; e += 256) {
        int sl = e >> 5, ol = e & 31;
        int s = st * 32 + sl, o = ot * 32 + ol;
        size_t m = (size_t)b * 1024 + s;
        float sc = scale2[o];
        float v = (sc >= 0.f) ? gmax[m * 128 + o] : gmin[m * 128 + o];
        tile[sl][ol] = fmaxf(sc * v + shift2[o], 0.f);
    }
    __syncthreads();
    for (int e = tid; e < 1024; e += 256) {
        int ol = e >> 5, sl = e & 31;
        int s = st * 32 + sl, o = ot * 32 + ol;
        out1[(size_t)b * 131072 + (size_t)o * 1024 + s] = tile[sl][ol];
    }
}

// ---------------------------------------------------------------- launch
extern "C" void kernel_launch(void* const* d_in, const int* in_sizes, int n_in,
                              void* d_out, int out_size, void* d_ws, size_t ws_size,
                              hipStream_t stream) {
    const float* xyz   = (const float*)d_in[0];
    const float* pts   = (const float*)d_in[1];
    const float* W0    = (const float*)d_in[2];
    const float* b0    = (const float*)d_in[3];
    const float* g0    = (const float*)d_in[4];
    const float* beta0 = (const float*)d_in[5];
    const float* W1    = (const float*)d_in[6];
    const float* b1    = (const float*)d_in[7];
    const float* g1    = (const float*)d_in[8];
    const float* beta1 = (const float*)d_in[9];
    const float* W2    = (const float*)d_in[10];
    const float* b2    = (const float*)d_in[11];
    const float* g2    = (const float*)d_in[12];
    const float* beta2 = (const float*)d_in[13];

    float* out0 = (float*)d_out;                  // (B,3,1024)  = 49152
    float* out1 = (float*)d_out + 49152;          // (B,128,1024)

    char* w = (char*)d_ws;
    size_t off = 0;
    int*    idxbuf = (int*)(w + off);    off += (size_t)R_ * 4;
    float*  F      = (float*)(w + off);  off += (size_t)R_ * 6 * 4;
    float*  Y1     = (float*)(w + off);  off += (size_t)R_ * 64 * 4;
    float*  gmax   = (float*)(w + off);  off += (size_t)B_ * S_ * 128 * 4;
    float*  gmin   = (float*)(w + off);  off += (size_t)B_ * S_ * 128 * 4;
    float2* part   = (float2*)(w + off); off += (size_t)NBLK_ * 128 * 2 * 4;
    float*  ss     = (float*)(w + off);  off += 512 * 4;
    float* scale0 = ss,       *shift0 = ss + 64;
    float* scale1 = ss + 128, *shift1 = ss + 192;
    float* scale2 = ss + 256, *shift2 = ss + 384;

    fps_kernel<<<B_, 1024, 0, stream>>>(xyz, out0);
    ballq_kernel<<<(B_ * S_) / 4, 256, 0, stream>>>(xyz, out0, idxbuf);
    gather_stats0<<<NBLK_, 256, 0, stream>>>(xyz, pts, out0, idxbuf, W0, b0, F, part);
    reduce_stats<<<64, 256, 0, stream>>>(part, NBLK_, 64, g0, beta0, scale0, shift0);
    layer1_kernel<<<NBLK_, 256, 0, stream>>>(F, W0, b0, scale0, shift0, W1, b1, Y1, part);
    reduce_stats<<<64, 256, 0, stream>>>(part, NBLK_, 64, g1, beta1, scale1, shift1);
    layer2_kernel<<<NBLK_, 256, 0, stream>>>(Y1, scale1, shift1, W2, b2, gmax, gmin, part);
    reduce_stats<<<128, 256, 0, stream>>>(part, NBLK_, 128, g2, beta2, scale2, shift2);
    final_kernel<<<dim3(B_, 32, 4), 256, 0, stream>>>(gmax, gmin, scale2, shift2, out1);
}

// Round 2
// 1767.111 us; speedup vs baseline: 1.2799x; 1.2799x over previous
//
#include <hip/hip_runtime.h>

#define B_ 16
#define N_ 4096
#define S_ 1024
#define K_ 32
#define R_ (B_*S_*K_)   // 524288 rows
#define NBLK_ (R_/64)   // 8192 row-tiles of 64

// ---------------------------------------------------------------- FPS
// one block per batch, 1024 threads, 4 points/thread, f64 distances.
// Per iteration: value-only f64 max butterfly + in-wave index recovery via
// ballot, single barrier with parity-double-buffered candidate array,
// redundant 16-candidate reduce on every thread (no second barrier).
__global__ __launch_bounds__(1024) void fps_kernel(const float* __restrict__ xyz,
                                                   float* __restrict__ out0) {
    const int b = blockIdx.x;
    const int tid = threadIdx.x;
    const int lane = tid & 63, wid = tid >> 6;
    __shared__ float xs[N_], ys[N_], zs[N_];
    __shared__ double2 cand[2][16];
    const float* xb = xyz + (size_t)b * 3 * N_;

    double dpx[4], dpy[4], dpz[4], dp2[4], dist[4];
#pragma unroll
    for (int j = 0; j < 4; ++j) {
        int i = tid + j * 1024;
        float x = xb[i], y = xb[N_ + i], z = xb[2 * N_ + i];
        xs[i] = x; ys[i] = y; zs[i] = z;
        dpx[j] = (double)x; dpy[j] = (double)y; dpz[j] = (double)z;
        dp2[j] = dpx[j] * dpx[j] + dpy[j] * dpy[j] + dpz[j] * dpz[j];
        dist[j] = 1e10;
    }
    __syncthreads();

    int far = 0;
    for (int s = 0; s < 1023; ++s) {
        float cxf = xs[far], cyf = ys[far], czf = zs[far];
        if (tid == 0) {
            out0[(size_t)b * 3072 + s]        = cxf;
            out0[(size_t)b * 3072 + 1024 + s] = cyf;
            out0[(size_t)b * 3072 + 2048 + s] = czf;
        }
        double cx = (double)cxf, cy = (double)cyf, cz = (double)czf;
        double c2 = cx * cx + cy * cy + cz * cz;
#pragma unroll
        for (int j = 0; j < 4; ++j) {
            double dot = dpx[j] * cx + dpy[j] * cy + dpz[j] * cz;
            double d = fma(-2.0, dot, dp2[j] + c2);
            dist[j] = fmin(dist[j], d);
        }
        double wmax = fmax(fmax(dist[0], dist[1]), fmax(dist[2], dist[3]));
#pragma unroll
        for (int m = 1; m < 64; m <<= 1)
            wmax = fmax(wmax, __shfl_xor(wmax, m, 64));
        // in-wave index recovery (ties have measure zero in random data)
        bool m0 = (dist[0] == wmax), m1 = (dist[1] == wmax);
        bool m2 = (dist[2] == wmax), m3 = (dist[3] == wmax);
        int j = m0 ? 0 : (m1 ? 1 : (m2 ? 2 : 3));
        unsigned long long eq = __ballot(m0 | m1 | m2 | m3);
        int src = (int)__builtin_ctzll(eq);          // eq != 0: wave max lives here
        int myidx = tid + j * 1024;
        int widx_v = __shfl(myidx, src, 64);
        int buf = s & 1;
        if (lane == 0)
            cand[buf][wid] = make_double2(wmax, __longlong_as_double((long long)widx_v));
        __syncthreads();
        double bv = cand[buf][0].x;
        long long bidx = __double_as_longlong(cand[buf][0].y);
#pragma unroll
        for (int w = 1; w < 16; ++w) {
            double2 c = cand[buf][w];
            bool g = c.x > bv;
            bv = g ? c.x : bv;
            bidx = g ? __double_as_longlong(c.y) : bidx;
        }
        far = (int)bidx;
    }
    if (tid == 0) {
        out0[(size_t)b * 3072 + 1023]        = xs[far];
        out0[(size_t)b * 3072 + 1024 + 1023] = ys[far];
        out0[(size_t)b * 3072 + 2048 + 1023] = zs[far];
    }
}

// ---------------------------------------------------------------- ball query
// one wave per centroid; first-32-ascending-index semantics via ballot compaction
__global__ __launch_bounds__(256) void ballq_kernel(const float* __restrict__ xyz,
                                                    const float* __restrict__ out0,
                                                    int* __restrict__ idxbuf) {
    int wid = threadIdx.x >> 6, lane = threadIdx.x & 63;
    int m = blockIdx.x * 4 + wid;          // centroid id < 16384
    int b = m >> 10, s = m & 1023;
    const float* xb = xyz + (size_t)b * 3 * N_;
    double cx = (double)out0[b * 3072 + s];
    double cy = (double)out0[b * 3072 + 1024 + s];
    double cz = (double)out0[b * 3072 + 2048 + s];
    double c2 = cx * cx + cy * cy + cz * cz;
    const double rr = 0.4 * 0.4;
    int* ob = idxbuf + (size_t)m * K_;
    int cnt = 0, first = -1;
    for (int ch = 0; ch < N_ / 64; ++ch) {
        int i = ch * 64 + lane;
        double x = (double)xb[i], y = (double)xb[N_ + i], z = (double)xb[2 * N_ + i];
        double p2 = x * x + y * y + z * z;
        double dot = cx * x + cy * y + cz * z;
        double sqr = (c2 + p2) - 2.0 * dot;
        bool in = !(sqr > rr);
        unsigned long long mask = __ballot(in);
        if (in) {
            int pos = cnt + __popcll(mask & ((1ull << lane) - 1ull));
            if (pos < K_) ob[pos] = i;
        }
        if (cnt == 0 && mask) first = ch * 64 + (__ffsll((long long)mask) - 1);
        cnt += __popcll(mask);
        if (cnt >= K_) break;
    }
    if (cnt < K_ && lane >= cnt && lane < K_) ob[lane] = first;
}

// ---------------------------------------------------------------- gather + layer0 stats
__global__ __launch_bounds__(256) void gather_stats0(
        const float* __restrict__ xyz, const float* __restrict__ pts,
        const float* __restrict__ out0, const int* __restrict__ idxbuf,
        const float* __restrict__ W0, const float* __restrict__ b0,
        float* __restrict__ F, float2* __restrict__ part) {
    __shared__ float Fs[64][6];
    __shared__ float W0s[384];
    __shared__ float b0s[64];
    __shared__ float2 red[4][64];
    int tid = threadIdx.x;
    long rowbase = (long)blockIdx.x * 64;
    if (tid < 64) {
        long r = rowbase + tid;
        int b = (int)(r >> 15);
        int rem = (int)(r & 32767);
        int s = rem >> 5;
        int i = idxbuf[r];
        const float* xb = xyz + (size_t)b * 3 * N_;
        const float* pb = pts + (size_t)b * 3 * N_;
        float cx = out0[b * 3072 + s], cy = out0[b * 3072 + 1024 + s], cz = out0[b * 3072 + 2048 + s];
        float f[6];
        f[0] = xb[i] - cx; f[1] = xb[N_ + i] - cy; f[2] = xb[2 * N_ + i] - cz;
        f[3] = pb[i];      f[4] = pb[N_ + i];      f[5] = pb[2 * N_ + i];
        float* Fg = F + (size_t)r * 6;
#pragma unroll
        for (int c = 0; c < 6; ++c) { Fs[tid][c] = f[c]; Fg[c] = f[c]; }
        b0s[tid] = b0[tid];
    }
    for (int t = tid; t < 384; t += 256) W0s[t] = W0[t];
    __syncthreads();
    int o = tid & 63, rg = tid >> 6;
    float w[6];
#pragma unroll
    for (int c = 0; c < 6; ++c) w[c] = W0s[o * 6 + c];
    float sum = 0.f, sq = 0.f;
#pragma unroll
    for (int rr = 0; rr < 16; ++rr) {
        int rl = rg * 16 + rr;
        float y = b0s[o];
#pragma unroll
        for (int c = 0; c < 6; ++c) y += Fs[rl][c] * w[c];
        sum += y; sq += y * y;
    }
    red[rg][o] = make_float2(sum, sq);
    __syncthreads();
    if (tid < 64) {
        float2 t0 = red[0][tid], t1 = red[1][tid], t2 = red[2][tid], t3 = red[3][tid];
        part[(size_t)blockIdx.x * 64 + tid] =
            make_float2(t0.x + t1.x + t2.x + t3.x, t0.y + t1.y + t2.y + t3.y);
    }
}

// ---------------------------------------------------------------- BN stats reduce
__global__ __launch_bounds__(256) void reduce_stats(const float2* __restrict__ part,
                                                    int nblk, int C,
                                                    const float* __restrict__ g,
                                                    const float* __restrict__ beta,
                                                    float* __restrict__ scale,
                                                    float* __restrict__ shift) {
    int o = blockIdx.x;
    int tid = threadIdx.x;
    double s = 0.0, q = 0.0;
    for (int i = tid; i < nblk; i += 256) {
        float2 v = part[(size_t)i * C + o];
        s += (double)v.x; q += (double)v.y;
    }
    __shared__ double ss[256], qq[256];
    ss[tid] = s; qq[tid] = q;
    __syncthreads();
    for (int m = 128; m > 0; m >>= 1) {
        if (tid < m) { ss[tid] += ss[tid + m]; qq[tid] += qq[tid + m]; }
        __syncthreads();
    }
    if (tid == 0) {
        const double Rd = (double)R_;
        double mean = ss[0] / Rd;
        double var = qq[0] / Rd - mean * mean;
        double sc = (double)g[o] / sqrt(var + 1e-5);
        scale[o] = (float)sc;
        shift[o] = (float)((double)beta[o] - mean * sc);
    }
}

// ---------------------------------------------------------------- layer1 GEMM (recompute layer0 + BN0 + relu)
__global__ __launch_bounds__(256) void layer1_kernel(
        const float* __restrict__ F, const float* __restrict__ W0,
        const float* __restrict__ b0, const float* __restrict__ scale0,
        const float* __restrict__ shift0, const float* __restrict__ W1,
        const float* __restrict__ b1, float* __restrict__ Y1,
        float2* __restrict__ part) {
    __shared__ float Fs[64][6];
    __shared__ float W0s[384];
    __shared__ float b0s[64], sc0[64], sh0[64];
    __shared__ float Xs[64][68];
    __shared__ float W1s[64][68];
    __shared__ float2 red[16][64];
    int tid = threadIdx.x;
    long rowbase = (long)blockIdx.x * 64;
    for (int t = tid; t < 384; t += 256) { Fs[t / 6][t % 6] = F[rowbase * 6 + t]; W0s[t] = W0[t]; }
    if (tid < 64) { b0s[tid] = b0[tid]; sc0[tid] = scale0[tid]; sh0[tid] = shift0[tid]; }
    for (int t = tid; t < 4096; t += 256) { int o = t >> 6, c = t & 63; W1s[c][o] = W1[t]; }
    __syncthreads();
    {
        int o = tid & 63, rg = tid >> 6;
        float w[6];
#pragma unroll
        for (int c = 0; c < 6; ++c) w[c] = W0s[o * 6 + c];
        float sc = sc0[o], sh = sh0[o], bb = b0s[o];
#pragma unroll
        for (int rr = 0; rr < 16; ++rr) {
            int rl = rg * 16 + rr;
            float y = bb;
#pragma unroll
            for (int c = 0; c < 6; ++c) y += Fs[rl][c] * w[c];
            Xs[rl][o] = fmaxf(sc * y + sh, 0.f);
        }
    }
    __syncthreads();
    int cg = tid & 15, rgp = tid >> 4;   // cols cg*4.., rows rgp*4..
    float acc[4][4] = {};
    for (int c = 0; c < 64; ++c) {
        float xr[4];
#pragma unroll
        for (int rr = 0; rr < 4; ++rr) xr[rr] = Xs[rgp * 4 + rr][c];
        float4 wv = *(const float4*)&W1s[c][cg * 4];
#pragma unroll
        for (int rr = 0; rr < 4; ++rr) {
            acc[rr][0] += xr[rr] * wv.x; acc[rr][1] += xr[rr] * wv.y;
            acc[rr][2] += xr[rr] * wv.z; acc[rr][3] += xr[rr] * wv.w;
        }
    }
    float bb1[4];
#pragma unroll
    for (int cc = 0; cc < 4; ++cc) bb1[cc] = b1[cg * 4 + cc];
#pragma unroll
    for (int rr = 0; rr < 4; ++rr)
#pragma unroll
        for (int cc = 0; cc < 4; ++cc) acc[rr][cc] += bb1[cc];
    // write Y1
#pragma unroll
    for (int rr = 0; rr < 4; ++rr) {
        long r = rowbase + rgp * 4 + rr;
        float4 v = make_float4(acc[rr][0], acc[rr][1], acc[rr][2], acc[rr][3]);
        *(float4*)&Y1[r * 64 + cg * 4] = v;
    }
    // stats
#pragma unroll
    for (int cc = 0; cc < 4; ++cc) {
        float s = acc[0][cc] + acc[1][cc] + acc[2][cc] + acc[3][cc];
        float q = acc[0][cc] * acc[0][cc] + acc[1][cc] * acc[1][cc] +
                  acc[2][cc] * acc[2][cc] + acc[3][cc] * acc[3][cc];
        red[rgp][cg * 4 + cc] = make_float2(s, q);
    }
    __syncthreads();
    if (tid < 64) {
        float s = 0.f, q = 0.f;
#pragma unroll
        for (int rp = 0; rp < 16; ++rp) { float2 v = red[rp][tid]; s += v.x; q += v.y; }
        part[(size_t)blockIdx.x * 64 + tid] = make_float2(s, q);
    }
}

// ---------------------------------------------------------------- layer2 GEMM + per-(b,s) max/min + stats
__global__ __launch_bounds__(256) void layer2_kernel(
        const float* __restrict__ Y1, const float* __restrict__ scale1,
        const float* __restrict__ shift1, const float* __restrict__ W2,
        const float* __restrict__ b2, float* __restrict__ gmax,
        float* __restrict__ gmin, float2* __restrict__ part) {
    __shared__ float Xs[64][68];
    __shared__ float W2s[64][132];
    __shared__ float red[16][128];
    int tid = threadIdx.x;
    long rowbase = (long)blockIdx.x * 64;
    {
        int o = tid & 63, rg = tid >> 6;
        float sc = scale1[o], sh = shift1[o];
#pragma unroll
        for (int rr = 0; rr < 16; ++rr) {
            int rl = rg * 16 + rr;
            float y = Y1[(rowbase + rl) * 64 + o];
            Xs[rl][o] = fmaxf(sc * y + sh, 0.f);
        }
    }
    for (int t = tid; t < 8192; t += 256) { int o = t >> 6, c = t & 63; W2s[c][o] = W2[t]; }
    __syncthreads();
    int cg = tid & 15, rgp = tid >> 4;   // cols cg*8.., rows rgp*4..
    float acc[4][8] = {};
    for (int c = 0; c < 64; ++c) {
        float xr[4];
#pragma unroll
        for (int rr = 0; rr < 4; ++rr) xr[rr] = Xs[rgp * 4 + rr][c];
        float4 wa = *(const float4*)&W2s[c][cg * 8];
        float4 wb = *(const float4*)&W2s[c][cg * 8 + 4];
#pragma unroll
        for (int rr = 0; rr < 4; ++rr) {
            acc[rr][0] += xr[rr] * wa.x; acc[rr][1] += xr[rr] * wa.y;
            acc[rr][2] += xr[rr] * wa.z; acc[rr][3] += xr[rr] * wa.w;
            acc[rr][4] += xr[rr] * wb.x; acc[rr][5] += xr[rr] * wb.y;
            acc[rr][6] += xr[rr] * wb.z; acc[rr][7] += xr[rr] * wb.w;
        }
    }
#pragma unroll
    for (int j = 0; j < 8; ++j) {
        float bb = b2[cg * 8 + j];
#pragma unroll
        for (int rr = 0; rr < 4; ++rr) acc[rr][j] += bb;
    }
    // ---- pass 1: sum
#pragma unroll
    for (int j = 0; j < 8; ++j)
        red[rgp][cg * 8 + j] = acc[0][j] + acc[1][j] + acc[2][j] + acc[3][j];
    __syncthreads();
    float psum = 0.f;
    if (tid < 128) { for (int rp = 0; rp < 16; ++rp) psum += red[rp][tid]; }
    __syncthreads();
    // ---- pass 2: sumsq
#pragma unroll
    for (int j = 0; j < 8; ++j)
        red[rgp][cg * 8 + j] = acc[0][j] * acc[0][j] + acc[1][j] * acc[1][j] +
                               acc[2][j] * acc[2][j] + acc[3][j] * acc[3][j];
    __syncthreads();
    if (tid < 128) {
        float psq = 0.f;
        for (int rp = 0; rp < 16; ++rp) psq += red[rp][tid];
        part[(size_t)blockIdx.x * 128 + tid] = make_float2(psum, psq);
    }
    __syncthreads();
    // ---- pass 3: max (rows of one thread all lie in one k-group)
#pragma unroll
    for (int j = 0; j < 8; ++j)
        red[rgp][cg * 8 + j] = fmaxf(fmaxf(acc[0][j], acc[1][j]), fmaxf(acc[2][j], acc[3][j]));
    __syncthreads();
    {
        int gsel = tid >> 7, col = tid & 127;
        float mv = -3.0e38f;
        for (int rp = gsel * 8; rp < gsel * 8 + 8; ++rp) mv = fmaxf(mv, red[rp][col]);
        gmax[((size_t)blockIdx.x * 2 + gsel) * 128 + col] = mv;
    }
    __syncthreads();
    // ---- pass 4: min
#pragma unroll
    for (int j = 0; j < 8; ++j)
        red[rgp][cg * 8 + j] = fminf(fminf(acc[0][j], acc[1][j]), fminf(acc[2][j], acc[3][j]));
    __syncthreads();
    {
        int gsel = tid >> 7, col = tid & 127;
        float mv = 3.0e38f;
        for (int rp = gsel * 8; rp < gsel * 8 + 8; ++rp) mv = fminf(mv, red[rp][col]);
        gmin[((size_t)blockIdx.x * 2 + gsel) * 128 + col] = mv;
    }
}

// ---------------------------------------------------------------- final BN2 + relu + transpose
__global__ __launch_bounds__(256) void final_kernel(const float* __restrict__ gmax,
                                                    const float* __restrict__ gmin,
                                                    const float* __restrict__ scale2,
                                                    const float* __restrict__ shift2,
                                                    float* __restrict__ out1) {
    int b = blockIdx.x, st = blockIdx.y, ot = blockIdx.z;
    __shared__ float tile[32][33];
    int tid = threadIdx.x;
    for (int e = tid; e < 1024; e += 256) {
        int sl = e >> 5, ol = e & 31;
        int s = st * 32 + sl, o = ot * 32 + ol;
        size_t m = (size_t)b * 1024 + s;
        float sc = scale2[o];
        float v = (sc >= 0.f) ? gmax[m * 128 + o] : gmin[m * 128 + o];
        tile[sl][ol] = fmaxf(sc * v + shift2[o], 0.f);
    }
    __syncthreads();
    for (int e = tid; e < 1024; e += 256) {
        int ol = e >> 5, sl = e & 31;
        int s = st * 32 + sl, o = ot * 32 + ol;
        out1[(size_t)b * 131072 + (size_t)o * 1024 + s] = tile[sl][ol];
    }
}

// ---------------------------------------------------------------- launch
extern "C" void kernel_launch(void* const* d_in, const int* in_sizes, int n_in,
                              void* d_out, int out_size, void* d_ws, size_t ws_size,
                              hipStream_t stream) {
    const float* xyz   = (const float*)d_in[0];
    const float* pts   = (const float*)d_in[1];
    const float* W0    = (const float*)d_in[2];
    const float* b0    = (const float*)d_in[3];
    const float* g0    = (const float*)d_in[4];
    const float* beta0 = (const float*)d_in[5];
    const float* W1    = (const float*)d_in[6];
    const float* b1    = (const float*)d_in[7];
    const float* g1    = (const float*)d_in[8];
    const float* beta1 = (const float*)d_in[9];
    const float* W2    = (const float*)d_in[10];
    const float* b2    = (const float*)d_in[11];
    const float* g2    = (const float*)d_in[12];
    const float* beta2 = (const float*)d_in[13];

    float* out0 = (float*)d_out;                  // (B,3,1024)  = 49152
    float* out1 = (float*)d_out + 49152;          // (B,128,1024)

    char* w = (char*)d_ws;
    size_t off = 0;
    int*    idxbuf = (int*)(w + off);    off += (size_t)R_ * 4;
    float*  F      = (float*)(w + off);  off += (size_t)R_ * 6 * 4;
    float*  Y1     = (float*)(w + off);  off += (size_t)R_ * 64 * 4;
    float*  gmax   = (float*)(w + off);  off += (size_t)B_ * S_ * 128 * 4;
    float*  gmin   = (float*)(w + off);  off += (size_t)B_ * S_ * 128 * 4;
    float2* part   = (float2*)(w + off); off += (size_t)NBLK_ * 128 * 2 * 4;
    float*  ss     = (float*)(w + off);  off += 512 * 4;
    float* scale0 = ss,       *shift0 = ss + 64;
    float* scale1 = ss + 128, *shift1 = ss + 192;
    float* scale2 = ss + 256, *shift2 = ss + 384;

    fps_kernel<<<B_, 1024, 0, stream>>>(xyz, out0);
    ballq_kernel<<<(B_ * S_) / 4, 256, 0, stream>>>(xyz, out0, idxbuf);
    gather_stats0<<<NBLK_, 256, 0, stream>>>(xyz, pts, out0, idxbuf, W0, b0, F, part);
    reduce_stats<<<64, 256, 0, stream>>>(part, NBLK_, 64, g0, beta0, scale0, shift0);
    layer1_kernel<<<NBLK_, 256, 0, stream>>>(F, W0, b0, scale0, shift0, W1, b1, Y1, part);
    reduce_stats<<<64, 256, 0, stream>>>(part, NBLK_, 64, g1, beta1, scale1, shift1);
    layer2_kernel<<<NBLK_, 256, 0, stream>>>(Y1, scale1, shift1, W2, b2, gmax, gmin, part);
    reduce_stats<<<128, 256, 0, stream>>>(part, NBLK_, 128, g2, beta2, scale2, shift2);
    final_kernel<<<dim3(B_, 32, 4), 256, 0, stream>>>(gmax, gmin, scale2, shift2, out1);
}

// Round 3
// 1208.495 us; speedup vs baseline: 1.8715x; 1.4622x over previous
//
#include <hip/hip_runtime.h>

#define B_ 16
#define N_ 4096
#define S_ 1024
#define K_ 32
#define R_ (B_*S_*K_)   // 524288 rows
#define NBLK_ (R_/64)   // 8192 row-tiles of 64

// ---------------------------------------------------------------- FPS
// one block per batch, 512 threads (8 waves), 8 points/thread, f64 distances.
// (dist,idx) packed into one u64 key (positive-f64 bits are u64-monotone;
// low 12 mantissa bits replaced by point idx). Per iteration: f64 fmax tree,
// 6-level u64 shuffle butterfly, single barrier, 8-candidate 3-level
// shuffle readback -> far via readfirstlane.
__global__ __launch_bounds__(512) void fps_kernel(const float* __restrict__ xyz,
                                                  float* __restrict__ out0) {
    const int b = blockIdx.x;
    const int tid = threadIdx.x;
    const int lane = tid & 63, wid = tid >> 6;       // 8 waves
    __shared__ float xs[N_], ys[N_], zs[N_];
    __shared__ unsigned long long cand[2][8];
    const float* xb = xyz + (size_t)b * 3 * N_;

    double nx[8], ny[8], nz[8], qq[8], dist[8];
#pragma unroll
    for (int j = 0; j < 8; ++j) {
        int i = tid + j * 512;
        float x = xb[i], y = xb[N_ + i], z = xb[2 * N_ + i];
        xs[i] = x; ys[i] = y; zs[i] = z;
        double dx = (double)x, dy = (double)y, dz = (double)z;
        qq[j] = dx * dx + dy * dy + dz * dz;
        nx[j] = -2.0 * dx; ny[j] = -2.0 * dy; nz[j] = -2.0 * dz;
        dist[j] = 1e10;
    }
    __syncthreads();

    int far = 0;
    for (int s = 0; s < 1023; ++s) {
        float cxf = xs[far], cyf = ys[far], czf = zs[far];
        if (tid == 0) {
            out0[(size_t)b * 3072 + s]        = cxf;
            out0[(size_t)b * 3072 + 1024 + s] = cyf;
            out0[(size_t)b * 3072 + 2048 + s] = czf;
        }
        double cx = (double)cxf, cy = (double)cyf, cz = (double)czf;
        double c2 = cx * cx + cy * cy + cz * cz;
#pragma unroll
        for (int j = 0; j < 8; ++j) {
            double d = fma(nx[j], cx, fma(ny[j], cy, fma(nz[j], cz, qq[j] + c2)));
            dist[j] = fmin(dist[j], d);
        }
        double m01 = fmax(dist[0], dist[1]), m23 = fmax(dist[2], dist[3]);
        double m45 = fmax(dist[4], dist[5]), m67 = fmax(dist[6], dist[7]);
        double lmax = fmax(fmax(fmax(m01, m23), fmax(m45, m67)), 0.0);
        int jj = 7;
#pragma unroll
        for (int j = 6; j >= 0; --j) jj = (dist[j] == lmax) ? j : jj;
        unsigned long long key =
            ((unsigned long long)__double_as_longlong(lmax) & ~0xFFFull) |
            (unsigned)(tid + jj * 512);
#pragma unroll
        for (int m = 1; m < 64; m <<= 1) {
            unsigned long long ok = __shfl_xor(key, m, 64);
            if (ok > key) key = ok;
        }
        int buf = s & 1;
        if (lane == 0) cand[buf][wid] = key;
        __syncthreads();
        unsigned long long k2 = cand[buf][lane & 7];
#pragma unroll
        for (int m = 1; m < 8; m <<= 1) {
            unsigned long long ok = __shfl_xor(k2, m, 64);
            if (ok > k2) k2 = ok;
        }
        far = (int)(__builtin_amdgcn_readfirstlane((unsigned)k2) & 0xFFFu);
    }
    if (tid == 0) {
        out0[(size_t)b * 3072 + 1023]        = xs[far];
        out0[(size_t)b * 3072 + 1024 + 1023] = ys[far];
        out0[(size_t)b * 3072 + 2048 + 1023] = zs[far];
    }
}

// ---------------------------------------------------------------- ball query
// one wave per centroid; first-32-ascending-index semantics via ballot compaction
__global__ __launch_bounds__(256) void ballq_kernel(const float* __restrict__ xyz,
                                                    const float* __restrict__ out0,
                                                    int* __restrict__ idxbuf) {
    int wid = threadIdx.x >> 6, lane = threadIdx.x & 63;
    int m = blockIdx.x * 4 + wid;          // centroid id < 16384
    int b = m >> 10, s = m & 1023;
    const float* xb = xyz + (size_t)b * 3 * N_;
    double cx = (double)out0[b * 3072 + s];
    double cy = (double)out0[b * 3072 + 1024 + s];
    double cz = (double)out0[b * 3072 + 2048 + s];
    double c2 = cx * cx + cy * cy + cz * cz;
    const double rr = 0.4 * 0.4;
    int* ob = idxbuf + (size_t)m * K_;
    int cnt = 0, first = -1;
    for (int ch = 0; ch < N_ / 64; ++ch) {
        int i = ch * 64 + lane;
        double x = (double)xb[i], y = (double)xb[N_ + i], z = (double)xb[2 * N_ + i];
        double p2 = x * x + y * y + z * z;
        double dot = cx * x + cy * y + cz * z;
        double sqr = (c2 + p2) - 2.0 * dot;
        bool in = !(sqr > rr);
        unsigned long long mask = __ballot(in);
        if (in) {
            int pos = cnt + __popcll(mask & ((1ull << lane) - 1ull));
            if (pos < K_) ob[pos] = i;
        }
        if (cnt == 0 && mask) first = ch * 64 + (__ffsll((long long)mask) - 1);
        cnt += __popcll(mask);
        if (cnt >= K_) break;
    }
    if (cnt < K_ && lane >= cnt && lane < K_) ob[lane] = first;
}

// ---------------------------------------------------------------- gather + layer0 stats
__global__ __launch_bounds__(256) void gather_stats0(
        const float* __restrict__ xyz, const float* __restrict__ pts,
        const float* __restrict__ out0, const int* __restrict__ idxbuf,
        const float* __restrict__ W0, const float* __restrict__ b0,
        float* __restrict__ F, float2* __restrict__ part) {
    __shared__ float Fs[64][6];
    __shared__ float W0s[384];
    __shared__ float b0s[64];
    __shared__ float2 red[4][64];
    int tid = threadIdx.x;
    long rowbase = (long)blockIdx.x * 64;
    if (tid < 64) {
        long r = rowbase + tid;
        int b = (int)(r >> 15);
        int rem = (int)(r & 32767);
        int s = rem >> 5;
        int i = idxbuf[r];
        const float* xb = xyz + (size_t)b * 3 * N_;
        const float* pb = pts + (size_t)b * 3 * N_;
        float cx = out0[b * 3072 + s], cy = out0[b * 3072 + 1024 + s], cz = out0[b * 3072 + 2048 + s];
        float f[6];
        f[0] = xb[i] - cx; f[1] = xb[N_ + i] - cy; f[2] = xb[2 * N_ + i] - cz;
        f[3] = pb[i];      f[4] = pb[N_ + i];      f[5] = pb[2 * N_ + i];
        float* Fg = F + (size_t)r * 6;
#pragma unroll
        for (int c = 0; c < 6; ++c) { Fs[tid][c] = f[c]; Fg[c] = f[c]; }
        b0s[tid] = b0[tid];
    }
    for (int t = tid; t < 384; t += 256) W0s[t] = W0[t];
    __syncthreads();
    int o = tid & 63, rg = tid >> 6;
    float w[6];
#pragma unroll
    for (int c = 0; c < 6; ++c) w[c] = W0s[o * 6 + c];
    float sum = 0.f, sq = 0.f;
#pragma unroll
    for (int rr = 0; rr < 16; ++rr) {
        int rl = rg * 16 + rr;
        float y = b0s[o];
#pragma unroll
        for (int c = 0; c < 6; ++c) y += Fs[rl][c] * w[c];
        sum += y; sq += y * y;
    }
    red[rg][o] = make_float2(sum, sq);
    __syncthreads();
    if (tid < 64) {
        float2 t0 = red[0][tid], t1 = red[1][tid], t2 = red[2][tid], t3 = red[3][tid];
        part[(size_t)blockIdx.x * 64 + tid] =
            make_float2(t0.x + t1.x + t2.x + t3.x, t0.y + t1.y + t2.y + t3.y);
    }
}

// ---------------------------------------------------------------- BN stats reduce
__global__ __launch_bounds__(256) void reduce_stats(const float2* __restrict__ part,
                                                    int nblk, int C,
                                                    const float* __restrict__ g,
                                                    const float* __restrict__ beta,
                                                    float* __restrict__ scale,
                                                    float* __restrict__ shift) {
    int o = blockIdx.x;
    int tid = threadIdx.x;
    double s = 0.0, q = 0.0;
    for (int i = tid; i < nblk; i += 256) {
        float2 v = part[(size_t)i * C + o];
        s += (double)v.x; q += (double)v.y;
    }
    __shared__ double ss[256], qq[256];
    ss[tid] = s; qq[tid] = q;
    __syncthreads();
    for (int m = 128; m > 0; m >>= 1) {
        if (tid < m) { ss[tid] += ss[tid + m]; qq[tid] += qq[tid + m]; }
        __syncthreads();
    }
    if (tid == 0) {
        const double Rd = (double)R_;
        double mean = ss[0] / Rd;
        double var = qq[0] / Rd - mean * mean;
        double sc = (double)g[o] / sqrt(var + 1e-5);
        scale[o] = (float)sc;
        shift[o] = (float)((double)beta[o] - mean * sc);
    }
}

// ---------------------------------------------------------------- layer1 GEMM (recompute layer0 + BN0 + relu)
__global__ __launch_bounds__(256) void layer1_kernel(
        const float* __restrict__ F, const float* __restrict__ W0,
        const float* __restrict__ b0, const float* __restrict__ scale0,
        const float* __restrict__ shift0, const float* __restrict__ W1,
        const float* __restrict__ b1, float* __restrict__ Y1,
        float2* __restrict__ part) {
    __shared__ float Fs[64][6];
    __shared__ float W0s[384];
    __shared__ float b0s[64], sc0[64], sh0[64];
    __shared__ float Xs[64][68];
    __shared__ float W1s[64][68];
    __shared__ float2 red[16][64];
    int tid = threadIdx.x;
    long rowbase = (long)blockIdx.x * 64;
    for (int t = tid; t < 384; t += 256) { Fs[t / 6][t % 6] = F[rowbase * 6 + t]; W0s[t] = W0[t]; }
    if (tid < 64) { b0s[tid] = b0[tid]; sc0[tid] = scale0[tid]; sh0[tid] = shift0[tid]; }
    for (int t = tid; t < 4096; t += 256) { int o = t >> 6, c = t & 63; W1s[c][o] = W1[t]; }
    __syncthreads();
    {
        int o = tid & 63, rg = tid >> 6;
        float w[6];
#pragma unroll
        for (int c = 0; c < 6; ++c) w[c] = W0s[o * 6 + c];
        float sc = sc0[o], sh = sh0[o], bb = b0s[o];
#pragma unroll
        for (int rr = 0; rr < 16; ++rr) {
            int rl = rg * 16 + rr;
            float y = bb;
#pragma unroll
            for (int c = 0; c < 6; ++c) y += Fs[rl][c] * w[c];
            Xs[rl][o] = fmaxf(sc * y + sh, 0.f);
        }
    }
    __syncthreads();
    int cg = tid & 15, rgp = tid >> 4;   // cols cg*4.., rows rgp*4..
    float acc[4][4] = {};
    for (int c = 0; c < 64; ++c) {
        float xr[4];
#pragma unroll
        for (int rr = 0; rr < 4; ++rr) xr[rr] = Xs[rgp * 4 + rr][c];
        float4 wv = *(const float4*)&W1s[c][cg * 4];
#pragma unroll
        for (int rr = 0; rr < 4; ++rr) {
            acc[rr][0] += xr[rr] * wv.x; acc[rr][1] += xr[rr] * wv.y;
            acc[rr][2] += xr[rr] * wv.z; acc[rr][3] += xr[rr] * wv.w;
        }
    }
    float bb1[4];
#pragma unroll
    for (int cc = 0; cc < 4; ++cc) bb1[cc] = b1[cg * 4 + cc];
#pragma unroll
    for (int rr = 0; rr < 4; ++rr)
#pragma unroll
        for (int cc = 0; cc < 4; ++cc) acc[rr][cc] += bb1[cc];
    // write Y1
#pragma unroll
    for (int rr = 0; rr < 4; ++rr) {
        long r = rowbase + rgp * 4 + rr;
        float4 v = make_float4(acc[rr][0], acc[rr][1], acc[rr][2], acc[rr][3]);
        *(float4*)&Y1[r * 64 + cg * 4] = v;
    }
    // stats
#pragma unroll
    for (int cc = 0; cc < 4; ++cc) {
        float s = acc[0][cc] + acc[1][cc] + acc[2][cc] + acc[3][cc];
        float q = acc[0][cc] * acc[0][cc] + acc[1][cc] * acc[1][cc] +
                  acc[2][cc] * acc[2][cc] + acc[3][cc] * acc[3][cc];
        red[rgp][cg * 4 + cc] = make_float2(s, q);
    }
    __syncthreads();
    if (tid < 64) {
        float s = 0.f, q = 0.f;
#pragma unroll
        for (int rp = 0; rp < 16; ++rp) { float2 v = red[rp][tid]; s += v.x; q += v.y; }
        part[(size_t)blockIdx.x * 64 + tid] = make_float2(s, q);
    }
}

// ---------------------------------------------------------------- layer2 GEMM + per-(b,s) max/min + stats
__global__ __launch_bounds__(256) void layer2_kernel(
        const float* __restrict__ Y1, const float* __restrict__ scale1,
        const float* __restrict__ shift1, const float* __restrict__ W2,
        const float* __restrict__ b2, float* __restrict__ gmax,
        float* __restrict__ gmin, float2* __restrict__ part) {
    __shared__ float Xs[64][68];
    __shared__ float W2s[64][132];
    __shared__ float red[16][128];
    int tid = threadIdx.x;
    long rowbase = (long)blockIdx.x * 64;
    {
        int o = tid & 63, rg = tid >> 6;
        float sc = scale1[o], sh = shift1[o];
#pragma unroll
        for (int rr = 0; rr < 16; ++rr) {
            int rl = rg * 16 + rr;
            float y = Y1[(rowbase + rl) * 64 + o];
            Xs[rl][o] = fmaxf(sc * y + sh, 0.f);
        }
    }
    for (int t = tid; t < 8192; t += 256) { int o = t >> 6, c = t & 63; W2s[c][o] = W2[t]; }
    __syncthreads();
    int cg = tid & 15, rgp = tid >> 4;   // cols cg*8.., rows rgp*4..
    float acc[4][8] = {};
    for (int c = 0; c < 64; ++c) {
        float xr[4];
#pragma unroll
        for (int rr = 0; rr < 4; ++rr) xr[rr] = Xs[rgp * 4 + rr][c];
        float4 wa = *(const float4*)&W2s[c][cg * 8];
        float4 wb = *(const float4*)&W2s[c][cg * 8 + 4];
#pragma unroll
        for (int rr = 0; rr < 4; ++rr) {
            acc[rr][0] += xr[rr] * wa.x; acc[rr][1] += xr[rr] * wa.y;
            acc[rr][2] += xr[rr] * wa.z; acc[rr][3] += xr[rr] * wa.w;
            acc[rr][4] += xr[rr] * wb.x; acc[rr][5] += xr[rr] * wb.y;
            acc[rr][6] += xr[rr] * wb.z; acc[rr][7] += xr[rr] * wb.w;
        }
    }
#pragma unroll
    for (int j = 0; j < 8; ++j) {
        float bb = b2[cg * 8 + j];
#pragma unroll
        for (int rr = 0; rr < 4; ++rr) acc[rr][j] += bb;
    }
    // ---- pass 1: sum
#pragma unroll
    for (int j = 0; j < 8; ++j)
        red[rgp][cg * 8 + j] = acc[0][j] + acc[1][j] + acc[2][j] + acc[3][j];
    __syncthreads();
    float psum = 0.f;
    if (tid < 128) { for (int rp = 0; rp < 16; ++rp) psum += red[rp][tid]; }
    __syncthreads();
    // ---- pass 2: sumsq
#pragma unroll
    for (int j = 0; j < 8; ++j)
        red[rgp][cg * 8 + j] = acc[0][j] * acc[0][j] + acc[1][j] * acc[1][j] +
                               acc[2][j] * acc[2][j] + acc[3][j] * acc[3][j];
    __syncthreads();
    if (tid < 128) {
        float psq = 0.f;
        for (int rp = 0; rp < 16; ++rp) psq += red[rp][tid];
        part[(size_t)blockIdx.x * 128 + tid] = make_float2(psum, psq);
    }
    __syncthreads();
    // ---- pass 3: max (rows of one thread all lie in one k-group)
#pragma unroll
    for (int j = 0; j < 8; ++j)
        red[rgp][cg * 8 + j] = fmaxf(fmaxf(acc[0][j], acc[1][j]), fmaxf(acc[2][j], acc[3][j]));
    __syncthreads();
    {
        int gsel = tid >> 7, col = tid & 127;
        float mv = -3.0e38f;
        for (int rp = gsel * 8; rp < gsel * 8 + 8; ++rp) mv = fmaxf(mv, red[rp][col]);
        gmax[((size_t)blockIdx.x * 2 + gsel) * 128 + col] = mv;
    }
    __syncthreads();
    // ---- pass 4: min
#pragma unroll
    for (int j = 0; j < 8; ++j)
        red[rgp][cg * 8 + j] = fminf(fminf(acc[0][j], acc[1][j]), fminf(acc[2][j], acc[3][j]));
    __syncthreads();
    {
        int gsel = tid >> 7, col = tid & 127;
        float mv = 3.0e38f;
        for (int rp = gsel * 8; rp < gsel * 8 + 8; ++rp) mv = fminf(mv, red[rp][col]);
        gmin[((size_t)blockIdx.x * 2 + gsel) * 128 + col] = mv;
    }
}

// ---------------------------------------------------------------- final BN2 + relu + transpose
__global__ __launch_bounds__(256) void final_kernel(const float* __restrict__ gmax,
                                                    const float* __restrict__ gmin,
                                                    const float* __restrict__ scale2,
                                                    const float* __restrict__ shift2,
                                                    float* __restrict__ out1) {
    int b = blockIdx.x, st = blockIdx.y, ot = blockIdx.z;
    __shared__ float tile[32][33];
    int tid = threadIdx.x;
    for (int e = tid; e < 1024; e += 256) {
        int sl = e >> 5, ol = e & 31;
        int s = st * 32 + sl, o = ot * 32 + ol;
        size_t m = (size_t)b * 1024 + s;
        float sc = scale2[o];
        float v = (sc >= 0.f) ? gmax[m * 128 + o] : gmin[m * 128 + o];
        tile[sl][ol] = fmaxf(sc * v + shift2[o], 0.f);
    }
    __syncthreads();
    for (int e = tid; e < 1024; e += 256) {
        int ol = e >> 5, sl = e & 31;
        int s = st * 32 + sl, o = ot * 32 + ol;
        out1[(size_t)b * 131072 + (size_t)o * 1024 + s] = tile[sl][ol];
    }
}

// ---------------------------------------------------------------- launch
extern "C" void kernel_launch(void* const* d_in, const int* in_sizes, int n_in,
                              void* d_out, int out_size, void* d_ws, size_t ws_size,
                              hipStream_t stream) {
    const float* xyz   = (const float*)d_in[0];
    const float* pts   = (const float*)d_in[1];
    const float* W0    = (const float*)d_in[2];
    const float* b0    = (const float*)d_in[3];
    const float* g0    = (const float*)d_in[4];
    const float* beta0 = (const float*)d_in[5];
    const float* W1    = (const float*)d_in[6];
    const float* b1    = (const float*)d_in[7];
    const float* g1    = (const float*)d_in[8];
    const float* beta1 = (const float*)d_in[9];
    const float* W2    = (const float*)d_in[10];
    const float* b2    = (const float*)d_in[11];
    const float* g2    = (const float*)d_in[12];
    const float* beta2 = (const float*)d_in[13];

    float* out0 = (float*)d_out;                  // (B,3,1024)  = 49152
    float* out1 = (float*)d_out + 49152;          // (B,128,1024)

    char* w = (char*)d_ws;
    size_t off = 0;
    int*    idxbuf = (int*)(w + off);    off += (size_t)R_ * 4;
    float*  F      = (float*)(w + off);  off += (size_t)R_ * 6 * 4;
    float*  Y1     = (float*)(w + off);  off += (size_t)R_ * 64 * 4;
    float*  gmax   = (float*)(w + off);  off += (size_t)B_ * S_ * 128 * 4;
    float*  gmin   = (float*)(w + off);  off += (size_t)B_ * S_ * 128 * 4;
    float2* part   = (float2*)(w + off); off += (size_t)NBLK_ * 128 * 2 * 4;
    float*  ss     = (float*)(w + off);  off += 512 * 4;
    float* scale0 = ss,       *shift0 = ss + 64;
    float* scale1 = ss + 128, *shift1 = ss + 192;
    float* scale2 = ss + 256, *shift2 = ss + 384;

    fps_kernel<<<B_, 512, 0, stream>>>(xyz, out0);
    ballq_kernel<<<(B_ * S_) / 4, 256, 0, stream>>>(xyz, out0, idxbuf);
    gather_stats0<<<NBLK_, 256, 0, stream>>>(xyz, pts, out0, idxbuf, W0, b0, F, part);
    reduce_stats<<<64, 256, 0, stream>>>(part, NBLK_, 64, g0, beta0, scale0, shift0);
    layer1_kernel<<<NBLK_, 256, 0, stream>>>(F, W0, b0, scale0, shift0, W1, b1, Y1, part);
    reduce_stats<<<64, 256, 0, stream>>>(part, NBLK_, 64, g1, beta1, scale1, shift1);
    layer2_kernel<<<NBLK_, 256, 0, stream>>>(Y1, scale1, shift1, W2, b2, gmax, gmin, part);
    reduce_stats<<<128, 256, 0, stream>>>(part, NBLK_, 128, g2, beta2, scale2, shift2);
    final_kernel<<<dim3(B_, 32, 4), 256, 0, stream>>>(gmax, gmin, scale2, shift2, out1);
}

// Round 4
// 1042.073 us; speedup vs baseline: 2.1704x; 1.1597x over previous
//
#include <hip/hip_runtime.h>

#define B_ 16
#define N_ 4096
#define S_ 1024
#define K_ 32
#define R_ (B_*S_*K_)   // 524288 rows
#define NBLK_ (R_/64)   // 8192 row-tiles of 64

// max(key, dpp_move<CTRL>(key)) on a packed u64 key, identity-preserving
// (old value kept where the DPP source lane is invalid, bound_ctrl=0).
template <int CTRL>
__device__ __forceinline__ unsigned long long dpp_max_u64(unsigned long long key) {
    int lo = (int)(unsigned)key;
    int hi = (int)(unsigned)(key >> 32);
    int olo = __builtin_amdgcn_update_dpp(lo, lo, CTRL, 0xF, 0xF, false);
    int ohi = __builtin_amdgcn_update_dpp(hi, hi, CTRL, 0xF, 0xF, false);
    unsigned long long other =
        ((unsigned long long)(unsigned)ohi << 32) | (unsigned)olo;
    return other > key ? other : key;
}

// ---------------------------------------------------------------- FPS
// one block per batch, 512 threads (8 waves), 8 points/thread, f64 distances.
// (dist,idx) packed into one u64 key (positive-f64 bits are u64-monotone; low
// 12 mantissa bits carry point idx). Wave reduce: 6-step DPP max
// (row_shr 1/2/4/8 + row_bcast15/31 -> lane63). Cross-wave: lane63 ds_write,
// one barrier, 8-periodic cand read + quad_perm/row_ror DPP combine,
// readfirstlane -> far.
__global__ __launch_bounds__(512) void fps_kernel(const float* __restrict__ xyz,
                                                  float* __restrict__ out0) {
    const int b = blockIdx.x;
    const int tid = threadIdx.x;
    const int lane = tid & 63, wid = tid >> 6;       // 8 waves
    __shared__ float4 p4[N_];
    __shared__ unsigned long long cand[2][8];
    const float* xb = xyz + (size_t)b * 3 * N_;

    double nx[8], ny[8], nz[8], qq[8], dist[8];
#pragma unroll
    for (int j = 0; j < 8; ++j) {
        int i = tid + j * 512;
        float x = xb[i], y = xb[N_ + i], z = xb[2 * N_ + i];
        p4[i] = make_float4(x, y, z, 0.f);
        double dx = (double)x, dy = (double)y, dz = (double)z;
        qq[j] = dx * dx + dy * dy + dz * dz;
        nx[j] = -2.0 * dx; ny[j] = -2.0 * dy; nz[j] = -2.0 * dz;
        dist[j] = 1e10;
    }
    __syncthreads();

    int far = 0;
    for (int s = 0; s < 1023; ++s) {
        float4 c = p4[far];
        if (tid == 0) {
            out0[(size_t)b * 3072 + s]        = c.x;
            out0[(size_t)b * 3072 + 1024 + s] = c.y;
            out0[(size_t)b * 3072 + 2048 + s] = c.z;
        }
        double cx = (double)c.x, cy = (double)c.y, cz = (double)c.z;
        double c2 = cx * cx + cy * cy + cz * cz;
#pragma unroll
        for (int j = 0; j < 8; ++j) {
            double d = fma(nx[j], cx, fma(ny[j], cy, fma(nz[j], cz, qq[j] + c2)));
            dist[j] = fmin(dist[j], d);
        }
        double m01 = fmax(dist[0], dist[1]), m23 = fmax(dist[2], dist[3]);
        double m45 = fmax(dist[4], dist[5]), m67 = fmax(dist[6], dist[7]);
        double lmax = fmax(fmax(fmax(m01, m23), fmax(m45, m67)), 0.0);
        int jj = 7;
#pragma unroll
        for (int j = 6; j >= 0; --j) jj = (dist[j] == lmax) ? j : jj;
        unsigned long long key =
            ((unsigned long long)__double_as_longlong(lmax) & ~0xFFFull) |
            (unsigned)(tid + jj * 512);
        // wave-level max via DPP (lane 63 ends with the wave max)
        key = dpp_max_u64<0x111>(key);   // row_shr:1
        key = dpp_max_u64<0x112>(key);   // row_shr:2
        key = dpp_max_u64<0x114>(key);   // row_shr:4
        key = dpp_max_u64<0x118>(key);   // row_shr:8
        key = dpp_max_u64<0x142>(key);   // row_bcast15
        key = dpp_max_u64<0x143>(key);   // row_bcast31
        int buf = s & 1;
        if (lane == 63) cand[buf][wid] = key;
        __syncthreads();
        unsigned long long k2 = cand[buf][lane & 7];
        k2 = dpp_max_u64<0xB1>(k2);      // quad_perm xor1
        k2 = dpp_max_u64<0x4E>(k2);      // quad_perm xor2
        k2 = dpp_max_u64<0x124>(k2);     // row_ror:4 (8-periodic -> lane0 global)
        far = (int)(__builtin_amdgcn_readfirstlane((unsigned)k2) & 0xFFFu);
    }
    if (tid == 0) {
        float4 c = p4[far];
        out0[(size_t)b * 3072 + 1023]        = c.x;
        out0[(size_t)b * 3072 + 1024 + 1023] = c.y;
        out0[(size_t)b * 3072 + 2048 + 1023] = c.z;
    }
}

// ---------------------------------------------------------------- ball query
// one wave per centroid; first-32-ascending-index semantics via ballot compaction
__global__ __launch_bounds__(256) void ballq_kernel(const float* __restrict__ xyz,
                                                    const float* __restrict__ out0,
                                                    int* __restrict__ idxbuf) {
    int wid = threadIdx.x >> 6, lane = threadIdx.x & 63;
    int m = blockIdx.x * 4 + wid;          // centroid id < 16384
    int b = m >> 10, s = m & 1023;
    const float* xb = xyz + (size_t)b * 3 * N_;
    double cx = (double)out0[b * 3072 + s];
    double cy = (double)out0[b * 3072 + 1024 + s];
    double cz = (double)out0[b * 3072 + 2048 + s];
    double c2 = cx * cx + cy * cy + cz * cz;
    const double rr = 0.4 * 0.4;
    int* ob = idxbuf + (size_t)m * K_;
    int cnt = 0, first = -1;
    for (int ch = 0; ch < N_ / 64; ++ch) {
        int i = ch * 64 + lane;
        double x = (double)xb[i], y = (double)xb[N_ + i], z = (double)xb[2 * N_ + i];
        double p2 = x * x + y * y + z * z;
        double dot = cx * x + cy * y + cz * z;
        double sqr = (c2 + p2) - 2.0 * dot;
        bool in = !(sqr > rr);
        unsigned long long mask = __ballot(in);
        if (in) {
            int pos = cnt + __popcll(mask & ((1ull << lane) - 1ull));
            if (pos < K_) ob[pos] = i;
        }
        if (cnt == 0 && mask) first = ch * 64 + (__ffsll((long long)mask) - 1);
        cnt += __popcll(mask);
        if (cnt >= K_) break;
    }
    if (cnt < K_ && lane >= cnt && lane < K_) ob[lane] = first;
}

// ---------------------------------------------------------------- gather + layer0 stats
__global__ __launch_bounds__(256) void gather_stats0(
        const float* __restrict__ xyz, const float* __restrict__ pts,
        const float* __restrict__ out0, const int* __restrict__ idxbuf,
        const float* __restrict__ W0, const float* __restrict__ b0,
        float* __restrict__ F, float2* __restrict__ part) {
    __shared__ float Fs[64][6];
    __shared__ float W0s[384];
    __shared__ float b0s[64];
    __shared__ float2 red[4][64];
    int tid = threadIdx.x;
    long rowbase = (long)blockIdx.x * 64;
    if (tid < 64) {
        long r = rowbase + tid;
        int b = (int)(r >> 15);
        int rem = (int)(r & 32767);
        int s = rem >> 5;
        int i = idxbuf[r];
        const float* xb = xyz + (size_t)b * 3 * N_;
        const float* pb = pts + (size_t)b * 3 * N_;
        float cx = out0[b * 3072 + s], cy = out0[b * 3072 + 1024 + s], cz = out0[b * 3072 + 2048 + s];
        float f[6];
        f[0] = xb[i] - cx; f[1] = xb[N_ + i] - cy; f[2] = xb[2 * N_ + i] - cz;
        f[3] = pb[i];      f[4] = pb[N_ + i];      f[5] = pb[2 * N_ + i];
        float* Fg = F + (size_t)r * 6;
#pragma unroll
        for (int c = 0; c < 6; ++c) { Fs[tid][c] = f[c]; Fg[c] = f[c]; }
        b0s[tid] = b0[tid];
    }
    for (int t = tid; t < 384; t += 256) W0s[t] = W0[t];
    __syncthreads();
    int o = tid & 63, rg = tid >> 6;
    float w[6];
#pragma unroll
    for (int c = 0; c < 6; ++c) w[c] = W0s[o * 6 + c];
    float sum = 0.f, sq = 0.f;
#pragma unroll
    for (int rr = 0; rr < 16; ++rr) {
        int rl = rg * 16 + rr;
        float y = b0s[o];
#pragma unroll
        for (int c = 0; c < 6; ++c) y += Fs[rl][c] * w[c];
        sum += y; sq += y * y;
    }
    red[rg][o] = make_float2(sum, sq);
    __syncthreads();
    if (tid < 64) {
        float2 t0 = red[0][tid], t1 = red[1][tid], t2 = red[2][tid], t3 = red[3][tid];
        part[(size_t)blockIdx.x * 64 + tid] =
            make_float2(t0.x + t1.x + t2.x + t3.x, t0.y + t1.y + t2.y + t3.y);
    }
}

// ---------------------------------------------------------------- BN stats reduce
__global__ __launch_bounds__(256) void reduce_stats(const float2* __restrict__ part,
                                                    int nblk, int C,
                                                    const float* __restrict__ g,
                                                    const float* __restrict__ beta,
                                                    float* __restrict__ scale,
                                                    float* __restrict__ shift) {
    int o = blockIdx.x;
    int tid = threadIdx.x;
    double s = 0.0, q = 0.0;
    for (int i = tid; i < nblk; i += 256) {
        float2 v = part[(size_t)i * C + o];
        s += (double)v.x; q += (double)v.y;
    }
    __shared__ double ss[256], qq[256];
    ss[tid] = s; qq[tid] = q;
    __syncthreads();
    for (int m = 128; m > 0; m >>= 1) {
        if (tid < m) { ss[tid] += ss[tid + m]; qq[tid] += qq[tid + m]; }
        __syncthreads();
    }
    if (tid == 0) {
        const double Rd = (double)R_;
        double mean = ss[0] / Rd;
        double var = qq[0] / Rd - mean * mean;
        double sc = (double)g[o] / sqrt(var + 1e-5);
        scale[o] = (float)sc;
        shift[o] = (float)((double)beta[o] - mean * sc);
    }
}

// ---------------------------------------------------------------- layer1 GEMM (recompute layer0 + BN0 + relu)
__global__ __launch_bounds__(256) void layer1_kernel(
        const float* __restrict__ F, const float* __restrict__ W0,
        const float* __restrict__ b0, const float* __restrict__ scale0,
        const float* __restrict__ shift0, const float* __restrict__ W1,
        const float* __restrict__ b1, float* __restrict__ Y1,
        float2* __restrict__ part) {
    __shared__ float Fs[64][6];
    __shared__ float W0s[384];
    __shared__ float b0s[64], sc0[64], sh0[64];
    __shared__ float Xs[64][68];
    __shared__ float W1s[64][68];
    __shared__ float2 red[16][64];
    int tid = threadIdx.x;
    long rowbase = (long)blockIdx.x * 64;
    for (int t = tid; t < 384; t += 256) { Fs[t / 6][t % 6] = F[rowbase * 6 + t]; W0s[t] = W0[t]; }
    if (tid < 64) { b0s[tid] = b0[tid]; sc0[tid] = scale0[tid]; sh0[tid] = shift0[tid]; }
    for (int t = tid; t < 4096; t += 256) { int o = t >> 6, c = t & 63; W1s[c][o] = W1[t]; }
    __syncthreads();
    {
        int o = tid & 63, rg = tid >> 6;
        float w[6];
#pragma unroll
        for (int c = 0; c < 6; ++c) w[c] = W0s[o * 6 + c];
        float sc = sc0[o], sh = sh0[o], bb = b0s[o];
#pragma unroll
        for (int rr = 0; rr < 16; ++rr) {
            int rl = rg * 16 + rr;
            float y = bb;
#pragma unroll
            for (int c = 0; c < 6; ++c) y += Fs[rl][c] * w[c];
            Xs[rl][o] = fmaxf(sc * y + sh, 0.f);
        }
    }
    __syncthreads();
    int cg = tid & 15, rgp = tid >> 4;   // cols cg*4.., rows rgp*4..
    float acc[4][4] = {};
    for (int c = 0; c < 64; ++c) {
        float xr[4];
#pragma unroll
        for (int rr = 0; rr < 4; ++rr) xr[rr] = Xs[rgp * 4 + rr][c];
        float4 wv = *(const float4*)&W1s[c][cg * 4];
#pragma unroll
        for (int rr = 0; rr < 4; ++rr) {
            acc[rr][0] += xr[rr] * wv.x; acc[rr][1] += xr[rr] * wv.y;
            acc[rr][2] += xr[rr] * wv.z; acc[rr][3] += xr[rr] * wv.w;
        }
    }
    float bb1[4];
#pragma unroll
    for (int cc = 0; cc < 4; ++cc) bb1[cc] = b1[cg * 4 + cc];
#pragma unroll
    for (int rr = 0; rr < 4; ++rr)
#pragma unroll
        for (int cc = 0; cc < 4; ++cc) acc[rr][cc] += bb1[cc];
    // write Y1
#pragma unroll
    for (int rr = 0; rr < 4; ++rr) {
        long r = rowbase + rgp * 4 + rr;
        float4 v = make_float4(acc[rr][0], acc[rr][1], acc[rr][2], acc[rr][3]);
        *(float4*)&Y1[r * 64 + cg * 4] = v;
    }
    // stats
#pragma unroll
    for (int cc = 0; cc < 4; ++cc) {
        float s = acc[0][cc] + acc[1][cc] + acc[2][cc] + acc[3][cc];
        float q = acc[0][cc] * acc[0][cc] + acc[1][cc] * acc[1][cc] +
                  acc[2][cc] * acc[2][cc] + acc[3][cc] * acc[3][cc];
        red[rgp][cg * 4 + cc] = make_float2(s, q);
    }
    __syncthreads();
    if (tid < 64) {
        float s = 0.f, q = 0.f;
#pragma unroll
        for (int rp = 0; rp < 16; ++rp) { float2 v = red[rp][tid]; s += v.x; q += v.y; }
        part[(size_t)blockIdx.x * 64 + tid] = make_float2(s, q);
    }
}

// ---------------------------------------------------------------- layer2 GEMM + per-(b,s) max/min + stats
__global__ __launch_bounds__(256) void layer2_kernel(
        const float* __restrict__ Y1, const float* __restrict__ scale1,
        const float* __restrict__ shift1, const float* __restrict__ W2,
        const float* __restrict__ b2, float* __restrict__ gmax,
        float* __restrict__ gmin, float2* __restrict__ part) {
    __shared__ float Xs[64][68];
    __shared__ float W2s[64][132];
    __shared__ float red[16][128];
    int tid = threadIdx.x;
    long rowbase = (long)blockIdx.x * 64;
    {
        int o = tid & 63, rg = tid >> 6;
        float sc = scale1[o], sh = shift1[o];
#pragma unroll
        for (int rr = 0; rr < 16; ++rr) {
            int rl = rg * 16 + rr;
            float y = Y1[(rowbase + rl) * 64 + o];
            Xs[rl][o] = fmaxf(sc * y + sh, 0.f);
        }
    }
    for (int t = tid; t < 8192; t += 256) { int o = t >> 6, c = t & 63; W2s[c][o] = W2[t]; }
    __syncthreads();
    int cg = tid & 15, rgp = tid >> 4;   // cols cg*8.., rows rgp*4..
    float acc[4][8] = {};
    for (int c = 0; c < 64; ++c) {
        float xr[4];
#pragma unroll
        for (int rr = 0; rr < 4; ++rr) xr[rr] = Xs[rgp * 4 + rr][c];
        float4 wa = *(const float4*)&W2s[c][cg * 8];
        float4 wb = *(const float4*)&W2s[c][cg * 8 + 4];
#pragma unroll
        for (int rr = 0; rr < 4; ++rr) {
            acc[rr][0] += xr[rr] * wa.x; acc[rr][1] += xr[rr] * wa.y;
            acc[rr][2] += xr[rr] * wa.z; acc[rr][3] += xr[rr] * wa.w;
            acc[rr][4] += xr[rr] * wb.x; acc[rr][5] += xr[rr] * wb.y;
            acc[rr][6] += xr[rr] * wb.z; acc[rr][7] += xr[rr] * wb.w;
        }
    }
#pragma unroll
    for (int j = 0; j < 8; ++j) {
        float bb = b2[cg * 8 + j];
#pragma unroll
        for (int rr = 0; rr < 4; ++rr) acc[rr][j] += bb;
    }
    // ---- pass 1: sum
#pragma unroll
    for (int j = 0; j < 8; ++j)
        red[rgp][cg * 8 + j] = acc[0][j] + acc[1][j] + acc[2][j] + acc[3][j];
    __syncthreads();
    float psum = 0.f;
    if (tid < 128) { for (int rp = 0; rp < 16; ++rp) psum += red[rp][tid]; }
    __syncthreads();
    // ---- pass 2: sumsq
#pragma unroll
    for (int j = 0; j < 8; ++j)
        red[rgp][cg * 8 + j] = acc[0][j] * acc[0][j] + acc[1][j] * acc[1][j] +
                               acc[2][j] * acc[2][j] + acc[3][j] * acc[3][j];
    __syncthreads();
    if (tid < 128) {
        float psq = 0.f;
        for (int rp = 0; rp < 16; ++rp) psq += red[rp][tid];
        part[(size_t)blockIdx.x * 128 + tid] = make_float2(psum, psq);
    }
    __syncthreads();
    // ---- pass 3: max (rows of one thread all lie in one k-group)
#pragma unroll
    for (int j = 0; j < 8; ++j)
        red[rgp][cg * 8 + j] = fmaxf(fmaxf(acc[0][j], acc[1][j]), fmaxf(acc[2][j], acc[3][j]));
    __syncthreads();
    {
        int gsel = tid >> 7, col = tid & 127;
        float mv = -3.0e38f;
        for (int rp = gsel * 8; rp < gsel * 8 + 8; ++rp) mv = fmaxf(mv, red[rp][col]);
        gmax[((size_t)blockIdx.x * 2 + gsel) * 128 + col] = mv;
    }
    __syncthreads();
    // ---- pass 4: min
#pragma unroll
    for (int j = 0; j < 8; ++j)
        red[rgp][cg * 8 + j] = fminf(fminf(acc[0][j], acc[1][j]), fminf(acc[2][j], acc[3][j]));
    __syncthreads();
    {
        int gsel = tid >> 7, col = tid & 127;
        float mv = 3.0e38f;
        for (int rp = gsel * 8; rp < gsel * 8 + 8; ++rp) mv = fminf(mv, red[rp][col]);
        gmin[((size_t)blockIdx.x * 2 + gsel) * 128 + col] = mv;
    }
}

// ---------------------------------------------------------------- final BN2 + relu + transpose
__global__ __launch_bounds__(256) void final_kernel(const float* __restrict__ gmax,
                                                    const float* __restrict__ gmin,
                                                    const float* __restrict__ scale2,
                                                    const float* __restrict__ shift2,
                                                    float* __restrict__ out1) {
    int b = blockIdx.x, st = blockIdx.y, ot = blockIdx.z;
    __shared__ float tile[32][33];
    int tid = threadIdx.x;
    for (int e = tid; e < 1024; e += 256) {
        int sl = e >> 5, ol = e & 31;
        int s = st * 32 + sl, o = ot * 32 + ol;
        size_t m = (size_t)b * 1024 + s;
        float sc = scale2[o];
        float v = (sc >= 0.f) ? gmax[m * 128 + o] : gmin[m * 128 + o];
        tile[sl][ol] = fmaxf(sc * v + shift2[o], 0.f);
    }
    __syncthreads();
    for (int e = tid; e < 1024; e += 256) {
        int ol = e >> 5, sl = e & 31;
        int s = st * 32 + sl, o = ot * 32 + ol;
        out1[(size_t)b * 131072 + (size_t)o * 1024 + s] = tile[sl][ol];
    }
}

// ---------------------------------------------------------------- launch
extern "C" void kernel_launch(void* const* d_in, const int* in_sizes, int n_in,
                              void* d_out, int out_size, void* d_ws, size_t ws_size,
                              hipStream_t stream) {
    const float* xyz   = (const float*)d_in[0];
    const float* pts   = (const float*)d_in[1];
    const float* W0    = (const float*)d_in[2];
    const float* b0    = (const float*)d_in[3];
    const float* g0    = (const float*)d_in[4];
    const float* beta0 = (const float*)d_in[5];
    const float* W1    = (const float*)d_in[6];
    const float* b1    = (const float*)d_in[7];
    const float* g1    = (const float*)d_in[8];
    const float* beta1 = (const float*)d_in[9];
    const float* W2    = (const float*)d_in[10];
    const float* b2    = (const float*)d_in[11];
    const float* g2    = (const float*)d_in[12];
    const float* beta2 = (const float*)d_in[13];

    float* out0 = (float*)d_out;                  // (B,3,1024)  = 49152
    float* out1 = (float*)d_out + 49152;          // (B,128,1024)

    char* w = (char*)d_ws;
    size_t off = 0;
    int*    idxbuf = (int*)(w + off);    off += (size_t)R_ * 4;
    float*  F      = (float*)(w + off);  off += (size_t)R_ * 6 * 4;
    float*  Y1     = (float*)(w + off);  off += (size_t)R_ * 64 * 4;
    float*  gmax   = (float*)(w + off);  off += (size_t)B_ * S_ * 128 * 4;
    float*  gmin   = (float*)(w + off);  off += (size_t)B_ * S_ * 128 * 4;
    float2* part   = (float2*)(w + off); off += (size_t)NBLK_ * 128 * 2 * 4;
    float*  ss     = (float*)(w + off);  off += 512 * 4;
    float* scale0 = ss,       *shift0 = ss + 64;
    float* scale1 = ss + 128, *shift1 = ss + 192;
    float* scale2 = ss + 256, *shift2 = ss + 384;

    fps_kernel<<<B_, 512, 0, stream>>>(xyz, out0);
    ballq_kernel<<<(B_ * S_) / 4, 256, 0, stream>>>(xyz, out0, idxbuf);
    gather_stats0<<<NBLK_, 256, 0, stream>>>(xyz, pts, out0, idxbuf, W0, b0, F, part);
    reduce_stats<<<64, 256, 0, stream>>>(part, NBLK_, 64, g0, beta0, scale0, shift0);
    layer1_kernel<<<NBLK_, 256, 0, stream>>>(F, W0, b0, scale0, shift0, W1, b1, Y1, part);
    reduce_stats<<<64, 256, 0, stream>>>(part, NBLK_, 64, g1, beta1, scale1, shift1);
    layer2_kernel<<<NBLK_, 256, 0, stream>>>(Y1, scale1, shift1, W2, b2, gmax, gmin, part);
    reduce_stats<<<128, 256, 0, stream>>>(part, NBLK_, 128, g2, beta2, scale2, shift2);
    final_kernel<<<dim3(B_, 32, 4), 256, 0, stream>>>(gmax, gmin, scale2, shift2, out1);
}